// Round 2
// baseline (113815.710 us; speedup 1.0000x reference)
//
#include <hip/hip_runtime.h>
#include <hip/hip_bf16.h>

#define N_EVENTS 50000
#define TS 512
#define NN 256
#define BATCH 512
#define SUB 64
#define LAMB 0.25f
#define NB 98

// ---------------- ws layout (float offsets) ----------------
#define OFF_INV   0            // 50048
#define OFF_WCUR  50048        // 131072 -> 181120
#define OFF_CH    181120       // 256
#define OFF_WN2   181376       // 256
#define OFF_RN    181632       // 256
#define OFF_PN    181888       // 256
#define OFF_PHI   182144       // 512
#define OFF_WIN   182656       // 512 -> 183168
#define OFF_S0P   183168       // nsplit * 131072
// G offset computed on host per ws_size tier.

#define RLF(v, l) __int_as_float(__builtin_amdgcn_readlane(__float_as_int(v), (l)))
#define RLI(v, l) __builtin_amdgcn_readlane((v), (l))
// wave-max step via DPP; invalid-source lanes keep old value (bound_ctrl=false)
#define DPP_MAXF(x, ctrl)                                                            \
    { int _s = __builtin_amdgcn_update_dpp(__float_as_int(x), __float_as_int(x),     \
                                           (ctrl), 0xF, 0xF, false);                 \
      (x) = fmaxf((x), __int_as_float(_s)); }

// ---------------- inv norm of each ts row ----------------
__global__ __launch_bounds__(256)
void inv_kernel(const float* __restrict__ ts, float* __restrict__ inv)
{
    __shared__ double red[256];
    const int e = blockIdx.x;
    const int d = threadIdx.x;
    const float* row = ts + (size_t)e * TS;
    float x0 = row[d], x1 = row[d + 256];
    red[d] = (double)x0 * x0 + (double)x1 * x1;
    __syncthreads();
    for (int st = 128; st > 0; st >>= 1) {
        if (d < st) red[d] += red[d + st];
        __syncthreads();
    }
    if (d == 0) inv[e] = (float)(1.0 / sqrt(red[0]));
}

// ---------------- init: ch from input, wn2/rn from W ----------------
__global__ __launch_bounds__(256)
void winit_kernel(const float* __restrict__ Wcur, const float* __restrict__ chin,
                  float* __restrict__ ch, float* __restrict__ wn2, float* __restrict__ rn)
{
    __shared__ double red[256];
    const int n = blockIdx.x;
    const int d = threadIdx.x;
    float w0 = Wcur[n * TS + d], w1 = Wcur[n * TS + d + 256];
    red[d] = (double)w0 * w0 + (double)w1 * w1;
    __syncthreads();
    for (int st = 128; st > 0; st >>= 1) {
        if (d < st) red[d] += red[d + st];
        __syncthreads();
    }
    if (d == 0) {
        double s = red[0];
        wn2[n] = (float)s;
        rn[n]  = (float)(1.0 / sqrt(s));
        ch[n]  = chin[n];
    }
}

// ---------------- S0 partials: tsn(batch) . W^T, K split by gridDim.z ----------------
__global__ __launch_bounds__(256)
void s0_gemm_kernel(const float* __restrict__ ts, const float* __restrict__ Wcur,
                    const float* __restrict__ inv, float* __restrict__ S0P,
                    int bstart, int bs)
{
    __shared__ float At[64][33];
    __shared__ float Bt[64][33];
    const int bf = blockIdx.x;   // event tile
    const int bn = blockIdx.y;   // neuron tile
    const int kz = blockIdx.z;
    if (bf * 64 >= bs) return;
    const int kchunk = TS / gridDim.z;
    const int k0 = kz * kchunk;
    const int tx = threadIdx.x & 15, ty = threadIdx.x >> 4;
    double acc[4][4] = {};
    for (int kt = k0; kt < k0 + kchunk; kt += 32) {
        for (int it = threadIdx.x; it < 64 * 32; it += 256) {
            int r = it >> 5, c = it & 31;
            int row = bf * 64 + r;
            At[r][c] = (row < bs) ? ts[(size_t)(bstart + row) * TS + kt + c] : 0.f;
            Bt[r][c] = Wcur[(bn * 64 + r) * TS + kt + c];
        }
        __syncthreads();
#pragma unroll
        for (int kk = 0; kk < 32; ++kk) {
            float av[4], bv[4];
#pragma unroll
            for (int i = 0; i < 4; ++i) av[i] = At[ty * 4 + i][kk];
#pragma unroll
            for (int j = 0; j < 4; ++j) bv[j] = Bt[tx * 4 + j][kk];
#pragma unroll
            for (int i = 0; i < 4; ++i)
#pragma unroll
                for (int j = 0; j < 4; ++j)
                    acc[i][j] += (double)av[i] * (double)bv[j];
        }
        __syncthreads();
    }
    float* out = S0P + (size_t)kz * (BATCH * NN);
#pragma unroll
    for (int i = 0; i < 4; ++i) {
        int f = bf * 64 + ty * 4 + i;
        if (f >= bs) continue;
        double iv = (double)inv[bstart + f];
#pragma unroll
        for (int j = 0; j < 4; ++j) {
            int n = bn * 64 + tx * 4 + j;
            out[f * NN + n] = (float)(acc[i][j] * iv);
        }
    }
}

// ---------------- G[e][f] = tsn_e . tsn_f (upper blocks); z = batch ----------------
__global__ __launch_bounds__(256)
void gram_kernel(const float* __restrict__ ts, const float* __restrict__ inv,
                 float* __restrict__ G, int zbase)
{
    const int b = zbase + blockIdx.z;
    const int bstart = b * BATCH;
    const int bs = min(BATCH, N_EVENTS - bstart);
    float* Gz = G + (size_t)blockIdx.z * (BATCH * BATCH);
    const int be = blockIdx.x, bf = blockIdx.y;
    if (bf < be) return;
    if (be * 64 >= bs || bf * 64 >= bs) return;
    __shared__ float At[64][33];
    __shared__ float Bt[64][33];
    const int tx = threadIdx.x & 15, ty = threadIdx.x >> 4;
    float acc[4][4] = {};
    for (int kt = 0; kt < TS; kt += 32) {
        for (int it = threadIdx.x; it < 64 * 32; it += 256) {
            int r = it >> 5, c = it & 31;
            int re = be * 64 + r, rf = bf * 64 + r;
            At[r][c] = (re < bs) ? ts[(size_t)(bstart + re) * TS + kt + c] : 0.f;
            Bt[r][c] = (rf < bs) ? ts[(size_t)(bstart + rf) * TS + kt + c] : 0.f;
        }
        __syncthreads();
#pragma unroll
        for (int kk = 0; kk < 32; ++kk) {
            float av[4], bv[4];
#pragma unroll
            for (int i = 0; i < 4; ++i) av[i] = At[ty * 4 + i][kk];
#pragma unroll
            for (int j = 0; j < 4; ++j) bv[j] = Bt[tx * 4 + j][kk];
#pragma unroll
            for (int i = 0; i < 4; ++i)
#pragma unroll
                for (int j = 0; j < 4; ++j)
                    acc[i][j] += av[i] * bv[j];
        }
        __syncthreads();
    }
#pragma unroll
    for (int i = 0; i < 4; ++i) {
        int e = be * 64 + ty * 4 + i;
        if (e >= bs) continue;
        float ie = inv[bstart + e];
#pragma unroll
        for (int j = 0; j < 4; ++j) {
            int f = bf * 64 + tx * 4 + j;
            if (f < bs) Gz[e * BATCH + f] = acc[i][j] * ie * inv[bstart + f];
        }
    }
}

// ---------------- the sequential per-event chain ----------------
__global__ __launch_bounds__(256)
void seq_step_kernel(const float* __restrict__ S0P, const float* __restrict__ Gb,
                     float* __restrict__ ch_g, const float* __restrict__ wn2_g,
                     const float* __restrict__ rn_g, float* __restrict__ Pn_g,
                     float* __restrict__ phi_g, int* __restrict__ win_g,
                     float* __restrict__ winners_out, int bstart, int bs, int nsplit)
{
    __shared__ float ACC[SUB * NN];   // swizzled: phys col = (n + r) & 255
    __shared__ float GS[SUB * SUB];
    __shared__ float GL[SUB * SUB];
    __shared__ int   winL[BATCH];
    __shared__ float phiL[BATCH];

    const int tid = threadIdx.x;
    const int wid = tid >> 6;
    const int lane = tid & 63;

    float ch[4] = {0, 0, 0, 0}, wn2v[4] = {1, 1, 1, 1};
    float rn[4] = {1, 1, 1, 1}, Pn[4] = {1, 1, 1, 1};
    float Ssum = 1.f, sinv = 1.f;
    if (wid == 0) {
#pragma unroll
        for (int k = 0; k < 4; ++k) {
            int n = k * 64 + lane;
            ch[k]   = ch_g[n];
            wn2v[k] = wn2_g[n];
            rn[k]   = rn_g[n];
            Pn[k]   = 1.0f;
        }
        float loc = ch[0] + ch[1] + ch[2] + ch[3];
#pragma unroll
        for (int off = 32; off > 0; off >>= 1) loc += __shfl_xor(loc, off, 64);
        Ssum = loc;
        sinv = 1.0f / Ssum;
    }

    const int nsub = (bs + SUB - 1) >> 6;
    for (int sub = 0; sub < nsub; ++sub) {
        const int s0 = sub << 6;
        const int cnt = min(SUB, bs - s0);
        __syncthreads();   // previous sub fully consumed

        // load ACC rows = sum of S0 partials (swizzled)
        for (int it = tid; it < cnt * NN; it += 256) {
            int r = it >> 8, n = it & 255;
            int gi = (s0 + r) * NN + n;
            float v = 0.f;
            for (int z = 0; z < nsplit; ++z) v += S0P[z * (BATCH * NN) + gi];
            ACC[r * NN + ((n + r) & 255)] = v;
        }
        // load within-sub gram
        for (int it = tid; it < cnt * SUB; it += 256) {
            int t = it >> 6, f = it & 63;
            GS[t * SUB + f] = (f < cnt) ? Gb[(s0 + t) * BATCH + s0 + f] : 0.f;
        }
        __syncthreads();

        // lazy-apply prior events of this batch (LDS-staged G chunks)
        for (int base = 0; base < s0; base += 64) {
            for (int it = tid; it < 64 * 64; it += 256)
                GL[it] = Gb[(base + (it >> 6)) * BATCH + s0 + (it & 63)];
            int   wreg = winL[base + lane];
            float preg = phiL[base + lane];
            __syncthreads();
            for (int j = 0; j < 64; ++j) {
                int wj = RLI(wreg, j);
                if ((wj & 3) == wid) {
                    float pj = RLF(preg, j);
                    if (lane < cnt)
                        ACC[lane * NN + ((wj + lane) & 255)] += pj * GL[j * 64 + lane];
                }
            }
            __syncthreads();
        }

        // sequential steps on wave 0
        if (wid == 0) {
            float acur[4];
#pragma unroll
            for (int k = 0; k < 4; ++k) acur[k] = ACC[(k * 64 + lane) & 255];

            for (int t = 0; t < cnt; ++t) {
                const bool havenext = (t + 1 < cnt);
                float anext[4] = {0.f, 0.f, 0.f, 0.f};
                if (havenext) {
                    const int r = t + 1;
#pragma unroll
                    for (int k = 0; k < 4; ++k)
                        anext[k] = ACC[r * NN + ((k * 64 + lane + r) & 255)];
                }
                const int forig = t + 1 + lane;
                const float gval = GS[t * SUB + (forig & 63)];

                const float gmul = 256.0f * sinv;
                float beta[4], key[4];
                float kmax;
#pragma unroll
                for (int k = 0; k < 4; ++k) {
                    float dot = Pn[k] * acur[k];
                    beta[k] = dot * rn[k];
                    float frac = ch[k] * gmul;
                    float gain = __expf(LAMB * (1.0f - frac));
                    key[k] = gain * beta[k];
                }
                kmax = fmaxf(fmaxf(key[0], key[1]), fmaxf(key[2], key[3]));
                DPP_MAXF(kmax, 0x111); DPP_MAXF(kmax, 0x112); DPP_MAXF(kmax, 0x114);
                DPP_MAXF(kmax, 0x118); DPP_MAXF(kmax, 0x142); DPP_MAXF(kmax, 0x143);
                const float smax = RLF(kmax, 63);

                unsigned long long m0 = __ballot(key[0] == smax);
                unsigned long long m1 = __ballot(key[1] == smax);
                unsigned long long m2 = __ballot(key[2] == smax);
                unsigned long long m3 = __ballot(key[3] == smax);
                int ns = m0 ? (int)__builtin_ctzll(m0)
                       : m1 ? 64  + (int)__builtin_ctzll(m1)
                       : m2 ? 128 + (int)__builtin_ctzll(m2)
                            : 192 + (int)__builtin_ctzll(m3);
                ns = __builtin_amdgcn_readfirstlane(ns);
                const int owner = ns & 63, ks = ns >> 6;

                float bsel = (ks == 0) ? beta[0] : (ks == 1) ? beta[1] : (ks == 2) ? beta[2] : beta[3];
                float csel = (ks == 0) ? ch[0]   : (ks == 1) ? ch[1]   : (ks == 2) ? ch[2]   : ch[3];
                float asel = (ks == 0) ? acur[0] : (ks == 1) ? acur[1] : (ks == 2) ? acur[2] : acur[3];
                float psel = (ks == 0) ? Pn[0]   : (ks == 1) ? Pn[1]   : (ks == 2) ? Pn[2]   : Pn[3];
                const float betas = RLF(bsel, owner);
                const float chs   = RLF(csel, owner);
                const float dots  = RLF(psel * asel, owner);
                const float pold  = RLF(psel, owner);

                const float alpha = 0.01f / (1.0f + chs / 20000.0f);
                const float c    = alpha * betas;
                const float omc  = 1.0f - c;
                const float pnew = pold * omc;
                const float phi  = c / pnew;
                const float g1   = RLF(gval, 0);

#pragma unroll
                for (int k = 0; k < 4; ++k) {
                    bool me = (lane == owner) && (k == ks);
                    if (me) {
                        wn2v[k] = omc * omc * wn2v[k] + 2.f * c * omc * dots + c * c;
                        rn[k] = 1.0f / sqrtf(wn2v[k]);
                        ch[k] += 1.0f;
                        Pn[k] = pnew;
                        anext[k] += phi * g1;   // in-register fix for next row
                    }
                }
                // far-row LDS updates (f >= t+2)
                if (lane > 0 && forig < cnt)
                    ACC[forig * NN + ((ns + forig) & 255)] += phi * gval;

                const int ib = s0 + t;
                if (lane == 0) {
                    winL[ib] = ns; phiL[ib] = phi;
                    win_g[ib] = ns; phi_g[ib] = phi;
                    winners_out[bstart + ib] = (float)ns;
                }
                Ssum += 1.0f;
                sinv = 1.0f / Ssum;
                if (havenext) {
#pragma unroll
                    for (int k = 0; k < 4; ++k) acur[k] = anext[k];
                }
            }
        }
    }
    __syncthreads();
    if (wid == 0) {
#pragma unroll
        for (int k = 0; k < 4; ++k) {
            int n = k * 64 + lane;
            ch_g[n] = ch[k];
            Pn_g[n] = Pn[k];
        }
    }
}

// ---------------- materialize W for the batch, recompute wn2/rn ----------------
__global__ __launch_bounds__(256)
void wupdate_kernel(const float* __restrict__ ts, const float* __restrict__ inv,
                    const int* __restrict__ win_g, const float* __restrict__ phi_g,
                    const float* __restrict__ Pn_g, float* __restrict__ Wcur,
                    float* __restrict__ wn2_g, float* __restrict__ rn_g,
                    int bstart, int bs)
{
    __shared__ int   winS[BATCH];
    __shared__ float phiS[BATCH];
    __shared__ double red[256];
    const int n = blockIdx.x;
    const int d = threadIdx.x;
    for (int i = d; i < bs; i += 256) { winS[i] = win_g[i]; phiS[i] = phi_g[i]; }
    __syncthreads();
    const float Pf = Pn_g[n];
    float w0 = Wcur[n * TS + d];
    float w1 = Wcur[n * TS + d + 256];
    double a0 = 0.0, a1 = 0.0;
    for (int ib = 0; ib < bs; ++ib) {
        if (winS[ib] == n) {
            double coef = (double)phiS[ib] * (double)Pf;
            float iv = inv[bstart + ib];
            const float* tr = ts + (size_t)(bstart + ib) * TS;
            a0 += coef * (double)(tr[d] * iv);
            a1 += coef * (double)(tr[d + 256] * iv);
        }
    }
    w0 = (float)((double)Pf * (double)w0 + a0);
    w1 = (float)((double)Pf * (double)w1 + a1);
    Wcur[n * TS + d] = w0;
    Wcur[n * TS + d + 256] = w1;
    red[d] = (double)w0 * w0 + (double)w1 * w1;
    __syncthreads();
    for (int st = 128; st > 0; st >>= 1) {
        if (d < st) red[d] += red[d + st];
        __syncthreads();
    }
    if (d == 0) {
        double s = red[0];
        wn2_g[n] = (float)s;
        rn_g[n]  = (float)(1.0 / sqrt(s));
    }
}

// ---------------- final copy: W and ch into d_out ----------------
__global__ __launch_bounds__(256)
void final_kernel(const float* __restrict__ Wcur, const float* __restrict__ ch,
                  float* __restrict__ out)
{
    int i = blockIdx.x * 256 + threadIdx.x;
    if (i < NN * TS) out[N_EVENTS + i] = Wcur[i];
    else if (i < NN * TS + NN) out[N_EVENTS + i] = ch[i - NN * TS];
}

extern "C" void kernel_launch(void* const* d_in, const int* in_sizes, int n_in,
                              void* d_out, int out_size, void* d_ws, size_t ws_size,
                              hipStream_t stream)
{
    const float* ts   = (const float*)d_in[0];
    const float* W0   = (const float*)d_in[1];
    const float* chin = (const float*)d_in[2];
    float* out = (float*)d_out;
    float* ws  = (float*)d_ws;

    float* inv  = ws + OFF_INV;
    float* Wcur = ws + OFF_WCUR;
    float* ch   = ws + OFF_CH;
    float* wn2  = ws + OFF_WN2;
    float* rn   = ws + OFF_RN;
    float* Pn   = ws + OFF_PN;
    float* phi  = ws + OFF_PHI;
    int*   win  = (int*)(ws + OFF_WIN);
    float* S0P  = ws + OFF_S0P;

    // ws tiers: [big] 4-way K-split S0 + all-batch gram; [mid] per-batch gram;
    // [tiny] round-1 footprint (1 partial, per-batch gram).
    const size_t wsf = ws_size / sizeof(float);
    const size_t GELEMS = (size_t)BATCH * BATCH;
    int nsplit; size_t offG; int bigG;
    if (wsf >= (size_t)OFF_S0P + 4 * 131072 + (size_t)NB * GELEMS) {
        nsplit = 4; offG = (size_t)OFF_S0P + 4 * 131072; bigG = 1;
    } else if (wsf >= (size_t)OFF_S0P + 4 * 131072 + GELEMS) {
        nsplit = 4; offG = (size_t)OFF_S0P + 4 * 131072; bigG = 0;
    } else {
        nsplit = 1; offG = (size_t)OFF_S0P + 131072; bigG = 0;
    }
    float* G = ws + offG;

    hipMemcpyAsync(Wcur, W0, (size_t)NN * TS * sizeof(float),
                   hipMemcpyDeviceToDevice, stream);
    inv_kernel<<<N_EVENTS, 256, 0, stream>>>(ts, inv);
    winit_kernel<<<NN, 256, 0, stream>>>(Wcur, chin, ch, wn2, rn);
    if (bigG)
        gram_kernel<<<dim3(8, 8, NB), 256, 0, stream>>>(ts, inv, G, 0);

    const int nbatch = NB;
    for (int b = 0; b < nbatch; ++b) {
        int bstart = b * BATCH;
        int bs = min(BATCH, N_EVENTS - bstart);
        s0_gemm_kernel<<<dim3(8, 4, nsplit), 256, 0, stream>>>(ts, Wcur, inv, S0P,
                                                               bstart, bs);
        if (!bigG)
            gram_kernel<<<dim3(8, 8, 1), 256, 0, stream>>>(ts, inv, G, b);
        const float* Gb = bigG ? (G + (size_t)b * GELEMS) : G;
        seq_step_kernel<<<1, 256, 0, stream>>>(S0P, Gb, ch, wn2, rn, Pn, phi, win,
                                               out, bstart, bs, nsplit);
        wupdate_kernel<<<NN, 256, 0, stream>>>(ts, inv, win, phi, Pn, Wcur,
                                               wn2, rn, bstart, bs);
    }
    final_kernel<<<(NN * TS + NN + 255) / 256, 256, 0, stream>>>(Wcur, ch, out);
}

// Round 3
// 82645.941 us; speedup vs baseline: 1.3771x; 1.3771x over previous
//
#include <hip/hip_runtime.h>
#include <hip/hip_bf16.h>

#define N_EVENTS 50000
#define TS 512
#define NN 256
#define BATCH 512
#define SUB 64
#define LAMB 0.25f
#define NB 98

#define RLF(v, l) __int_as_float(__builtin_amdgcn_readlane(__float_as_int(v), (l)))
#define RLI(v, l) __builtin_amdgcn_readlane((v), (l))
#define DPP_MAXF(x, ctrl)                                                            \
    { int _s = __builtin_amdgcn_update_dpp(__float_as_int(x), __float_as_int(x),     \
                                           (ctrl), 0xF, 0xF, false);                 \
      (x) = fmaxf((x), __int_as_float(_s)); }

// ==================== shared small kernels ====================

__global__ __launch_bounds__(256)
void inv_kernel(const float* __restrict__ ts, float* __restrict__ inv)
{
    __shared__ double red[256];
    const int e = blockIdx.x;
    const int d = threadIdx.x;
    const float* row = ts + (size_t)e * TS;
    float x0 = row[d], x1 = row[d + 256];
    red[d] = (double)x0 * x0 + (double)x1 * x1;
    __syncthreads();
    for (int st = 128; st > 0; st >>= 1) {
        if (d < st) red[d] += red[d + st];
        __syncthreads();
    }
    if (d == 0) inv[e] = (float)(1.0 / sqrt(red[0]));
}

__global__ __launch_bounds__(256)
void init_kernel(const float* __restrict__ chin, float* __restrict__ ch,
                 float* Pn0, float* Pn1, float* phi0, float* phi1,
                 float* c0, float* c1, float* d0, float* d1,
                 int* w0, int* w1)
{
    int i = blockIdx.x * 256 + threadIdx.x;  // 0..511
    if (i < NN) { ch[i] = chin[i]; Pn0[i] = 1.f; Pn1[i] = 1.f; }
    if (i < BATCH) {
        phi0[i] = 0.f; phi1[i] = 0.f; c0[i] = 0.f; c1[i] = 0.f;
        d0[i] = 0.f; d1[i] = 0.f; w0[i] = 0; w1[i] = 0;
    }
}

// ==================== gram tile (device) ====================

__device__ void gram_tile(float* SH, const float* __restrict__ ts,
                          const float* __restrict__ inv,
                          int astart, int as, int bstart2, int bs2,
                          int be, int bf, float* __restrict__ outp, int transpose)
{
    float* At = SH;              // [64][33]
    float* Bt = SH + 64 * 33;
    if (be * 64 >= as || bf * 64 >= bs2) return;
    const int tx = threadIdx.x & 15, ty = threadIdx.x >> 4;
    float acc[4][4] = {};
    for (int kt = 0; kt < TS; kt += 32) {
        for (int it = threadIdx.x; it < 64 * 32; it += 256) {
            int r = it >> 5, c = it & 31;
            int ra = be * 64 + r, rb = bf * 64 + r;
            At[r * 33 + c] = (ra < as) ? ts[(size_t)(astart + ra) * TS + kt + c] : 0.f;
            Bt[r * 33 + c] = (rb < bs2) ? ts[(size_t)(bstart2 + rb) * TS + kt + c] : 0.f;
        }
        __syncthreads();
#pragma unroll
        for (int kk = 0; kk < 32; ++kk) {
            float av[4], bv[4];
#pragma unroll
            for (int i = 0; i < 4; ++i) av[i] = At[(ty * 4 + i) * 33 + kk];
#pragma unroll
            for (int j = 0; j < 4; ++j) bv[j] = Bt[(tx * 4 + j) * 33 + kk];
#pragma unroll
            for (int i = 0; i < 4; ++i)
#pragma unroll
                for (int j = 0; j < 4; ++j)
                    acc[i][j] += av[i] * bv[j];
        }
        __syncthreads();
    }
#pragma unroll
    for (int i = 0; i < 4; ++i) {
        int e = be * 64 + ty * 4 + i;
        if (e >= as) continue;
        float ie = inv[astart + e];
#pragma unroll
        for (int j = 0; j < 4; ++j) {
            int f = bf * 64 + tx * 4 + j;
            if (f >= bs2) continue;
            float v = acc[i][j] * ie * inv[bstart2 + f];
            if (transpose) outp[(size_t)f * BATCH + e] = v;
            else           outp[(size_t)e * BATCH + f] = v;
        }
    }
}

__global__ __launch_bounds__(256)
void gram_kernel(const float* __restrict__ ts, const float* __restrict__ inv,
                 float* __restrict__ outp, int astart, int as, int bstart2, int bs2,
                 int upper, int transpose)
{
    __shared__ float SHg[64 * 33 * 2];
    if (upper && (int)blockIdx.y < (int)blockIdx.x) return;
    gram_tile(SHg, ts, inv, astart, as, bstart2, bs2, blockIdx.x, blockIdx.y,
              outp, transpose);
}

// ==================== neuron body: wupdate + fused S2 ====================

__device__ void neuron_body(float* shf, double* red,
    const float* __restrict__ ts, const float* __restrict__ inv,
    const float* __restrict__ Wsrc, float* __restrict__ wdst,
    const int* __restrict__ winPrev, const float* __restrict__ phiPrev,
    const float* __restrict__ PnPrev,
    float* __restrict__ wn2W, float* __restrict__ S2W,
    const float* __restrict__ chbuf, float* __restrict__ chout,
    int n, int bprev_start, int bs_prev, int bnext_start, int bs_next)
{
    int* winS = (int*)shf;
    float* phiS = shf + 512;
    float* WL = shf + 1024;
    const int d = threadIdx.x;
    for (int i = d; i < bs_prev; i += 256) { winS[i] = winPrev[i]; phiS[i] = phiPrev[i]; }
    __syncthreads();
    const float Pf = PnPrev[n];
    float w0 = Wsrc[n * TS + d];
    float w1 = Wsrc[n * TS + d + 256];
    double a0 = 0.0, a1 = 0.0;
    for (int e = 0; e < bs_prev; ++e) {
        if (winS[e] == n) {
            double coef = (double)phiS[e];
            float iv = inv[bprev_start + e];
            const float* tr = ts + (size_t)(bprev_start + e) * TS;
            a0 += coef * (double)(tr[d] * iv);
            a1 += coef * (double)(tr[d + 256] * iv);
        }
    }
    w0 = (float)((double)Pf * ((double)w0 + a0));
    w1 = (float)((double)Pf * ((double)w1 + a1));
    wdst[n * TS + d] = w0;
    wdst[n * TS + d + 256] = w1;
    WL[d] = w0; WL[d + 256] = w1;
    if (wn2W) {
        red[d] = (double)w0 * w0 + (double)w1 * w1;
        __syncthreads();
        for (int st = 128; st > 0; st >>= 1) {
            if (d < st) red[d] += red[d + st];
            __syncthreads();
        }
        if (d == 0) wn2W[n] = (float)red[0];
    } else {
        __syncthreads();
    }
    if (bs_next > 0) {
#pragma unroll
        for (int rep = 0; rep < 2; ++rep) {
            int f = d + rep * 256;
            if (f < bs_next) {
                double acc = 0.0;
                const float* tr = ts + (size_t)(bnext_start + f) * TS;
                for (int k = 0; k < TS; ++k) acc += (double)tr[k] * (double)WL[k];
                S2W[f * NN + n] = (float)(acc * (double)inv[bnext_start + f]);
            }
        }
    }
    if (chout && d == 0) chout[n] = chbuf[n];
}

__global__ __launch_bounds__(256)
void neuron_kernel(const float* __restrict__ ts, const float* __restrict__ inv,
    const float* __restrict__ Wsrc, float* __restrict__ wdst,
    const int* __restrict__ winPrev, const float* __restrict__ phiPrev,
    const float* __restrict__ PnPrev,
    float* __restrict__ wn2W, float* __restrict__ S2W,
    const float* __restrict__ chbuf, float* __restrict__ chout,
    int bprev_start, int bs_prev, int bnext_start, int bs_next)
{
    __shared__ float SHN[1536];
    __shared__ double redN[256];
    neuron_body(SHN, redN, ts, inv, Wsrc, wdst, winPrev, phiPrev, PnPrev,
                wn2W, S2W, chbuf, chout, blockIdx.x,
                bprev_start, bs_prev, bnext_start, bs_next);
}

// ==================== fix kernel: S0corr + wn2 replay ====================

__global__ __launch_bounds__(256)
void fix_kernel(const float* __restrict__ S2r, const float* __restrict__ GxTr,
    const int* __restrict__ winPrev, const float* __restrict__ phiPrev,
    const float* __restrict__ cPrev, const float* __restrict__ dPrev,
    const float* __restrict__ PnPrev, const float* __restrict__ wn2b,
    float* __restrict__ S0corr, float* __restrict__ wn2start,
    int bs, int b0flag)
{
    __shared__ int winS[512];
    __shared__ float phiP[512];
    __shared__ float gr[512];
    __shared__ float cS[512];
    __shared__ float dS[512];
    const int tid = threadIdx.x;
    const int f = blockIdx.x;
    for (int i = tid; i < 512; i += 256) {
        int w = winPrev[i];
        winS[i] = w;
        phiP[i] = b0flag ? 0.f : phiPrev[i] * PnPrev[w];
        cS[i] = cPrev[i];
        dS[i] = dPrev[i];
        gr[i] = (b0flag || f >= bs) ? 0.f : GxTr[(size_t)f * BATCH + i];
    }
    __syncthreads();
    if (f < bs) {
        int n = tid;
        float acc = PnPrev[n] * S2r[f * NN + n];
        if (!b0flag) {
            for (int e = 0; e < 512; ++e)
                if (winS[e] == n) acc += phiP[e] * gr[e];
        }
        S0corr[f * NN + n] = acc;
    }
    if (f == 0 && tid < 64) {
        const int lane = tid;
        float w2[4];
#pragma unroll
        for (int k = 0; k < 4; ++k) w2[k] = wn2b[k * 64 + lane];
        for (int e = 0; e < 512; ++e) {
            float c = cS[e];
            if (c != 0.f) {
                int w = winS[e];
                int owner = w & 63, kk = w >> 6;
                float omc = 1.f - c;
                float t2 = 2.f * c * omc * dS[e] + c * c;
#pragma unroll
                for (int k = 0; k < 4; ++k)
                    if (lane == owner && k == kk) w2[k] = omc * omc * w2[k] + t2;
            }
        }
#pragma unroll
        for (int k = 0; k < 4; ++k) wn2start[k * 64 + lane] = w2[k];
    }
}

// ==================== block 0: sequential chain ====================

__device__ void block0_body(float* SH,
    const float* __restrict__ S0corr, const float* __restrict__ GwR,
    const float* __restrict__ wn2start, float* __restrict__ chbuf,
    int* __restrict__ winCur, float* __restrict__ phiCur,
    float* __restrict__ cCur, float* __restrict__ dotCur, float* __restrict__ PnCur,
    float* __restrict__ winners_out, int bstart, int bs)
{
    float* ACC = SH;                 // 16384 (swizzled col = (n+row)&255)
    float* GS  = SH + 16384;         // 4096
    float* GL  = SH + 20480;         // 4096
    int*   winL = (int*)(SH + 24576);// 512
    float* phiL = SH + 25088;        // 512
    const int tid = threadIdx.x, wid = tid >> 6, lane = tid & 63;

    float ch[4] = {0,0,0,0}, wn2v[4] = {1,1,1,1};
    float rn[4] = {1,1,1,1}, Pn[4] = {1,1,1,1}, al[4] = {0,0,0,0};
    float Ssum = 1.f, K2 = 0.f;
    if (wid == 0) {
#pragma unroll
        for (int k = 0; k < 4; ++k) {
            int n = k * 64 + lane;
            ch[k] = chbuf[n];
            wn2v[k] = wn2start[n];
            rn[k] = 1.0f / sqrtf(wn2v[k]);
            al[k] = 0.01f / (1.0f + ch[k] / 20000.0f);
        }
        float loc = ch[0] + ch[1] + ch[2] + ch[3];
#pragma unroll
        for (int off = 32; off > 0; off >>= 1) loc += __shfl_xor(loc, off, 64);
        Ssum = loc;
        K2 = -(LAMB * 256.0f * 1.44269504f) / Ssum;
    }

    const int nsub = (bs + SUB - 1) >> 6;
    for (int sub = 0; sub < nsub; ++sub) {
        const int s0 = sub << 6;
        const int cnt = min(SUB, bs - s0);
        __syncthreads();
        {   // stage corrected S0 (already P-folded) into ACC
            int n = tid;
            for (int f = 0; f < cnt; ++f)
                ACC[f * NN + ((n + f) & 255)] = S0corr[(s0 + f) * NN + n];
        }
        for (int it = tid; it < SUB * SUB; it += 256) {
            int t = it >> 6, f = it & 63;
            GS[it] = (t < cnt && f < cnt) ? GwR[(size_t)(s0 + t) * BATCH + s0 + f] : 0.f;
        }
        // within-batch lazy apply of earlier subs' events
        for (int base = 0; base < s0; base += 64) {
            for (int it = tid; it < 64 * 64; it += 256)
                GL[it] = GwR[(size_t)(base + (it >> 6)) * BATCH + s0 + (it & 63)];
            int wreg = winL[base + lane];
            float preg = phiL[base + lane];
            __syncthreads();
            for (int j = 0; j < 64; ++j) {
                int wj = RLI(wreg, j);
                if ((wj & 3) == wid) {
                    float pj = RLF(preg, j);
                    if (lane < cnt)
                        ACC[lane * NN + ((wj + lane) & 255)] += pj * GL[j * 64 + lane];
                }
            }
            __syncthreads();
        }
        __syncthreads();

        if (wid == 0) {
            float acur[4];
#pragma unroll
            for (int k = 0; k < 4; ++k) acur[k] = ACC[(k * 64 + lane) & 255];

            for (int t = 0; t < cnt; ++t) {
                const bool havenext = (t + 1 < cnt);
                float anext[4] = {0.f, 0.f, 0.f, 0.f};
                if (havenext) {
                    const int r = t + 1;
#pragma unroll
                    for (int k = 0; k < 4; ++k)
                        anext[k] = ACC[r * NN + ((k * 64 + lane + r) & 255)];
                }
                const int forig = t + 1 + lane;
                const float gval = GS[t * SUB + (forig & 63)];

                float beta[4], key[4];
#pragma unroll
                for (int k = 0; k < 4; ++k) {
                    float dot = Pn[k] * acur[k];
                    beta[k] = dot * rn[k];
                    key[k] = beta[k] * exp2f(K2 * ch[k]);
                }
                float kmax = fmaxf(fmaxf(key[0], key[1]), fmaxf(key[2], key[3]));
                DPP_MAXF(kmax, 0x111); DPP_MAXF(kmax, 0x112); DPP_MAXF(kmax, 0x114);
                DPP_MAXF(kmax, 0x118); DPP_MAXF(kmax, 0x142); DPP_MAXF(kmax, 0x143);
                const float smax = RLF(kmax, 63);

                unsigned long long m0 = __ballot(key[0] == smax);
                unsigned long long m1 = __ballot(key[1] == smax);
                unsigned long long m2 = __ballot(key[2] == smax);
                unsigned long long m3 = __ballot(key[3] == smax);
                int ns = m0 ? (int)__builtin_ctzll(m0)
                       : m1 ? 64  + (int)__builtin_ctzll(m1)
                       : m2 ? 128 + (int)__builtin_ctzll(m2)
                            : 192 + (int)__builtin_ctzll(m3);
                ns = __builtin_amdgcn_readfirstlane(ns);
                const int owner = ns & 63, ks = ns >> 6;

                float bsel = (ks == 0) ? beta[0] : (ks == 1) ? beta[1] : (ks == 2) ? beta[2] : beta[3];
                float asel = (ks == 0) ? acur[0] : (ks == 1) ? acur[1] : (ks == 2) ? acur[2] : acur[3];
                float psel = (ks == 0) ? Pn[0]   : (ks == 1) ? Pn[1]   : (ks == 2) ? Pn[2]   : Pn[3];
                float lsel = (ks == 0) ? al[0]   : (ks == 1) ? al[1]   : (ks == 2) ? al[2]   : al[3];
                const float betas  = RLF(bsel, owner);
                const float alphas = RLF(lsel, owner);
                const float dots   = RLF(psel * asel, owner);
                const float pold   = RLF(psel, owner);

                const float c    = alphas * betas;
                const float omc  = 1.0f - c;
                const float pnew = pold * omc;
                const float phi  = c / pnew;
                const float g1   = RLF(gval, 0);

#pragma unroll
                for (int k = 0; k < 4; ++k) {
                    if (lane == owner && k == ks) {
                        wn2v[k] = omc * omc * wn2v[k] + 2.f * c * omc * dots + c * c;
                        rn[k] = 1.0f / sqrtf(wn2v[k]);
                        ch[k] += 1.0f;
                        al[k] = 0.01f / (1.0f + ch[k] / 20000.0f);
                        Pn[k] = pnew;
                        anext[k] += phi * g1;
                    }
                }
                if (lane > 0 && forig < cnt)
                    ACC[forig * NN + ((ns + forig) & 255)] += phi * gval;

                const int ib = s0 + t;
                if (lane == 0) {
                    winL[ib] = ns; phiL[ib] = phi;
                    winCur[ib] = ns; phiCur[ib] = phi;
                    cCur[ib] = c; dotCur[ib] = dots;
                    winners_out[bstart + ib] = (float)ns;
                }
                Ssum += 1.0f;
                K2 = -(LAMB * 256.0f * 1.44269504f) / Ssum;
                if (havenext) {
#pragma unroll
                    for (int k = 0; k < 4; ++k) acur[k] = anext[k];
                }
            }
        }
    }
    __syncthreads();
    if (wid == 0) {
#pragma unroll
        for (int k = 0; k < 4; ++k) {
            int n = k * 64 + lane;
            chbuf[n] = ch[k];
            PnCur[n] = Pn[k];
        }
    }
}

// ==================== fused per-batch kernel ====================

__global__ __launch_bounds__(256)
void fusedA_kernel(const float* __restrict__ ts, const float* __restrict__ inv,
    const float* __restrict__ S0corr, const float* __restrict__ GwR,
    float* __restrict__ GwW, float* __restrict__ GxTW,
    const float* __restrict__ wn2start, float* __restrict__ chbuf,
    const int* __restrict__ winPrev, const float* __restrict__ phiPrev,
    const float* __restrict__ PnPrev,
    int* __restrict__ winCur, float* __restrict__ phiCur,
    float* __restrict__ cCur, float* __restrict__ dotCur, float* __restrict__ PnCur,
    float* __restrict__ Wcur, float* __restrict__ wn2W, float* __restrict__ S2W,
    float* __restrict__ out, int b, int bstart, int bs, int bnext_start, int bs_next)
{
    __shared__ float SH[25600];
    const int bx = blockIdx.x;
    if (bx == 0) {
        block0_body(SH, S0corr, GwR, wn2start, chbuf,
                    winCur, phiCur, cCur, dotCur, PnCur, out, bstart, bs);
    } else if (bx <= NN) {
        neuron_body(SH, (double*)(SH + 1536), ts, inv, Wcur, Wcur,
                    winPrev, phiPrev, PnPrev, wn2W, S2W, nullptr, nullptr,
                    bx - 1, bstart - BATCH, (b == 0) ? 0 : BATCH,
                    bnext_start, bs_next);
    } else {
        int job = bx - (NN + 1);  // 0..99
        if (bs_next <= 0) return;
        if (job < 64) {
            gram_tile(SH, ts, inv, bstart, bs, bnext_start, bs_next,
                      job >> 3, job & 7, GxTW, 1);
        } else {
            int jw = job - 64;
            int be = 0;
            while (jw >= 8 - be) { jw -= 8 - be; ++be; }
            int bf = be + jw;
            gram_tile(SH, ts, inv, bnext_start, bs_next, bnext_start, bs_next,
                      be, bf, GwW, 0);
        }
    }
}

// ==================== fallback path (round-2, proven) ====================

__global__ __launch_bounds__(256)
void winit_kernel(const float* __restrict__ Wcur, const float* __restrict__ chin,
                  float* __restrict__ ch, float* __restrict__ wn2, float* __restrict__ rn)
{
    __shared__ double red[256];
    const int n = blockIdx.x;
    const int d = threadIdx.x;
    float w0 = Wcur[n * TS + d], w1 = Wcur[n * TS + d + 256];
    red[d] = (double)w0 * w0 + (double)w1 * w1;
    __syncthreads();
    for (int st = 128; st > 0; st >>= 1) {
        if (d < st) red[d] += red[d + st];
        __syncthreads();
    }
    if (d == 0) {
        double s = red[0];
        wn2[n] = (float)s;
        rn[n]  = (float)(1.0 / sqrt(s));
        ch[n]  = chin[n];
    }
}

__global__ __launch_bounds__(256)
void s0_gemm_kernel(const float* __restrict__ ts, const float* __restrict__ Wcur,
                    const float* __restrict__ inv, float* __restrict__ S0P,
                    int bstart, int bs)
{
    __shared__ float At[64][33];
    __shared__ float Bt[64][33];
    const int bf = blockIdx.x;
    const int bn = blockIdx.y;
    if (bf * 64 >= bs) return;
    const int tx = threadIdx.x & 15, ty = threadIdx.x >> 4;
    double acc[4][4] = {};
    for (int kt = 0; kt < TS; kt += 32) {
        for (int it = threadIdx.x; it < 64 * 32; it += 256) {
            int r = it >> 5, c = it & 31;
            int row = bf * 64 + r;
            At[r][c] = (row < bs) ? ts[(size_t)(bstart + row) * TS + kt + c] : 0.f;
            Bt[r][c] = Wcur[(bn * 64 + r) * TS + kt + c];
        }
        __syncthreads();
#pragma unroll
        for (int kk = 0; kk < 32; ++kk) {
            float av[4], bv[4];
#pragma unroll
            for (int i = 0; i < 4; ++i) av[i] = At[ty * 4 + i][kk];
#pragma unroll
            for (int j = 0; j < 4; ++j) bv[j] = Bt[tx * 4 + j][kk];
#pragma unroll
            for (int i = 0; i < 4; ++i)
#pragma unroll
                for (int j = 0; j < 4; ++j)
                    acc[i][j] += (double)av[i] * (double)bv[j];
        }
        __syncthreads();
    }
#pragma unroll
    for (int i = 0; i < 4; ++i) {
        int f = bf * 64 + ty * 4 + i;
        if (f >= bs) continue;
        double iv = (double)inv[bstart + f];
#pragma unroll
        for (int j = 0; j < 4; ++j) {
            int n = bn * 64 + tx * 4 + j;
            S0P[f * NN + n] = (float)(acc[i][j] * iv);
        }
    }
}

__global__ __launch_bounds__(256)
void seq_step_kernel(const float* __restrict__ S0P, const float* __restrict__ Gb,
                     float* __restrict__ ch_g, const float* __restrict__ wn2_g,
                     const float* __restrict__ rn_g, float* __restrict__ Pn_g,
                     float* __restrict__ phi_g, int* __restrict__ win_g,
                     float* __restrict__ winners_out, int bstart, int bs)
{
    __shared__ float ACC[SUB * NN];
    __shared__ float GS[SUB * SUB];
    __shared__ float GL[SUB * SUB];
    __shared__ int   winL[BATCH];
    __shared__ float phiL[BATCH];

    const int tid = threadIdx.x;
    const int wid = tid >> 6;
    const int lane = tid & 63;

    float ch[4] = {0, 0, 0, 0}, wn2v[4] = {1, 1, 1, 1};
    float rn[4] = {1, 1, 1, 1}, Pn[4] = {1, 1, 1, 1};
    float Ssum = 1.f, sinv = 1.f;
    if (wid == 0) {
#pragma unroll
        for (int k = 0; k < 4; ++k) {
            int n = k * 64 + lane;
            ch[k]   = ch_g[n];
            wn2v[k] = wn2_g[n];
            rn[k]   = rn_g[n];
            Pn[k]   = 1.0f;
        }
        float loc = ch[0] + ch[1] + ch[2] + ch[3];
#pragma unroll
        for (int off = 32; off > 0; off >>= 1) loc += __shfl_xor(loc, off, 64);
        Ssum = loc;
        sinv = 1.0f / Ssum;
    }

    const int nsub = (bs + SUB - 1) >> 6;
    for (int sub = 0; sub < nsub; ++sub) {
        const int s0 = sub << 6;
        const int cnt = min(SUB, bs - s0);
        __syncthreads();

        for (int it = tid; it < cnt * NN; it += 256) {
            int r = it >> 8, n = it & 255;
            ACC[r * NN + ((n + r) & 255)] = S0P[(s0 + r) * NN + n];
        }
        for (int it = tid; it < cnt * SUB; it += 256) {
            int t = it >> 6, f = it & 63;
            GS[t * SUB + f] = (f < cnt) ? Gb[(s0 + t) * BATCH + s0 + f] : 0.f;
        }
        __syncthreads();

        for (int base = 0; base < s0; base += 64) {
            for (int it = tid; it < 64 * 64; it += 256)
                GL[it] = Gb[(base + (it >> 6)) * BATCH + s0 + (it & 63)];
            int   wreg = winL[base + lane];
            float preg = phiL[base + lane];
            __syncthreads();
            for (int j = 0; j < 64; ++j) {
                int wj = RLI(wreg, j);
                if ((wj & 3) == wid) {
                    float pj = RLF(preg, j);
                    if (lane < cnt)
                        ACC[lane * NN + ((wj + lane) & 255)] += pj * GL[j * 64 + lane];
                }
            }
            __syncthreads();
        }

        if (wid == 0) {
            float acur[4];
#pragma unroll
            for (int k = 0; k < 4; ++k) acur[k] = ACC[(k * 64 + lane) & 255];

            for (int t = 0; t < cnt; ++t) {
                const bool havenext = (t + 1 < cnt);
                float anext[4] = {0.f, 0.f, 0.f, 0.f};
                if (havenext) {
                    const int r = t + 1;
#pragma unroll
                    for (int k = 0; k < 4; ++k)
                        anext[k] = ACC[r * NN + ((k * 64 + lane + r) & 255)];
                }
                const int forig = t + 1 + lane;
                const float gval = GS[t * SUB + (forig & 63)];

                const float gmul = 256.0f * sinv;
                float beta[4], key[4];
                float kmax;
#pragma unroll
                for (int k = 0; k < 4; ++k) {
                    float dot = Pn[k] * acur[k];
                    beta[k] = dot * rn[k];
                    float frac = ch[k] * gmul;
                    float gain = __expf(LAMB * (1.0f - frac));
                    key[k] = gain * beta[k];
                }
                kmax = fmaxf(fmaxf(key[0], key[1]), fmaxf(key[2], key[3]));
                DPP_MAXF(kmax, 0x111); DPP_MAXF(kmax, 0x112); DPP_MAXF(kmax, 0x114);
                DPP_MAXF(kmax, 0x118); DPP_MAXF(kmax, 0x142); DPP_MAXF(kmax, 0x143);
                const float smax = RLF(kmax, 63);

                unsigned long long m0 = __ballot(key[0] == smax);
                unsigned long long m1 = __ballot(key[1] == smax);
                unsigned long long m2 = __ballot(key[2] == smax);
                unsigned long long m3 = __ballot(key[3] == smax);
                int ns = m0 ? (int)__builtin_ctzll(m0)
                       : m1 ? 64  + (int)__builtin_ctzll(m1)
                       : m2 ? 128 + (int)__builtin_ctzll(m2)
                            : 192 + (int)__builtin_ctzll(m3);
                ns = __builtin_amdgcn_readfirstlane(ns);
                const int owner = ns & 63, ks = ns >> 6;

                float bsel = (ks == 0) ? beta[0] : (ks == 1) ? beta[1] : (ks == 2) ? beta[2] : beta[3];
                float csel = (ks == 0) ? ch[0]   : (ks == 1) ? ch[1]   : (ks == 2) ? ch[2]   : ch[3];
                float asel = (ks == 0) ? acur[0] : (ks == 1) ? acur[1] : (ks == 2) ? acur[2] : acur[3];
                float psel = (ks == 0) ? Pn[0]   : (ks == 1) ? Pn[1]   : (ks == 2) ? Pn[2]   : Pn[3];
                const float betas = RLF(bsel, owner);
                const float chs   = RLF(csel, owner);
                const float dots  = RLF(psel * asel, owner);
                const float pold  = RLF(psel, owner);

                const float alpha = 0.01f / (1.0f + chs / 20000.0f);
                const float c    = alpha * betas;
                const float omc  = 1.0f - c;
                const float pnew = pold * omc;
                const float phi  = c / pnew;
                const float g1   = RLF(gval, 0);

#pragma unroll
                for (int k = 0; k < 4; ++k) {
                    bool me = (lane == owner) && (k == ks);
                    if (me) {
                        wn2v[k] = omc * omc * wn2v[k] + 2.f * c * omc * dots + c * c;
                        rn[k] = 1.0f / sqrtf(wn2v[k]);
                        ch[k] += 1.0f;
                        Pn[k] = pnew;
                        anext[k] += phi * g1;
                    }
                }
                if (lane > 0 && forig < cnt)
                    ACC[forig * NN + ((ns + forig) & 255)] += phi * gval;

                const int ib = s0 + t;
                if (lane == 0) {
                    winL[ib] = ns; phiL[ib] = phi;
                    win_g[ib] = ns; phi_g[ib] = phi;
                    winners_out[bstart + ib] = (float)ns;
                }
                Ssum += 1.0f;
                sinv = 1.0f / Ssum;
                if (havenext) {
#pragma unroll
                    for (int k = 0; k < 4; ++k) acur[k] = anext[k];
                }
            }
        }
        __syncthreads();
    }

    if (wid == 0) {
#pragma unroll
        for (int k = 0; k < 4; ++k) {
            int n = k * 64 + lane;
            ch_g[n] = ch[k];
            Pn_g[n] = Pn[k];
        }
    }
}

__global__ __launch_bounds__(256)
void wupdate_kernel(const float* __restrict__ ts, const float* __restrict__ inv,
                    const int* __restrict__ win_g, const float* __restrict__ phi_g,
                    const float* __restrict__ Pn_g, float* __restrict__ Wcur,
                    float* __restrict__ wn2_g, float* __restrict__ rn_g,
                    int bstart, int bs)
{
    __shared__ int   winS[BATCH];
    __shared__ float phiS[BATCH];
    __shared__ double red[256];
    const int n = blockIdx.x;
    const int d = threadIdx.x;
    for (int i = d; i < bs; i += 256) { winS[i] = win_g[i]; phiS[i] = phi_g[i]; }
    __syncthreads();
    const float Pf = Pn_g[n];
    float w0 = Wcur[n * TS + d];
    float w1 = Wcur[n * TS + d + 256];
    double a0 = 0.0, a1 = 0.0;
    for (int ib = 0; ib < bs; ++ib) {
        if (winS[ib] == n) {
            double coef = (double)phiS[ib] * (double)Pf;
            float iv = inv[bstart + ib];
            const float* tr = ts + (size_t)(bstart + ib) * TS;
            a0 += coef * (double)(tr[d] * iv);
            a1 += coef * (double)(tr[d + 256] * iv);
        }
    }
    w0 = (float)((double)Pf * (double)w0 + a0);
    w1 = (float)((double)Pf * (double)w1 + a1);
    Wcur[n * TS + d] = w0;
    Wcur[n * TS + d + 256] = w1;
    red[d] = (double)w0 * w0 + (double)w1 * w1;
    __syncthreads();
    for (int st = 128; st > 0; st >>= 1) {
        if (d < st) red[d] += red[d + st];
        __syncthreads();
    }
    if (d == 0) {
        double s = red[0];
        wn2_g[n] = (float)s;
        rn_g[n]  = (float)(1.0 / sqrt(s));
    }
}

__global__ __launch_bounds__(256)
void final_kernel(const float* __restrict__ Wcur, const float* __restrict__ ch,
                  float* __restrict__ out)
{
    int i = blockIdx.x * 256 + threadIdx.x;
    if (i < NN * TS) out[N_EVENTS + i] = Wcur[i];
    else if (i < NN * TS + NN) out[N_EVENTS + i] = ch[i - NN * TS];
}

// ==================== host ====================

extern "C" void kernel_launch(void* const* d_in, const int* in_sizes, int n_in,
                              void* d_out, int out_size, void* d_ws, size_t ws_size,
                              hipStream_t stream)
{
    const float* ts   = (const float*)d_in[0];
    const float* W0   = (const float*)d_in[1];
    const float* chin = (const float*)d_in[2];
    float* out = (float*)d_out;
    float* ws  = (float*)d_ws;

    const size_t FULL_FLOATS = 1628544;  // ~6.52 MB
    if (ws_size >= FULL_FLOATS * sizeof(float)) {
        // -------- full pipelined path --------
        float* inv  = ws + 0;
        float* Wcur = ws + 50048;
        float* ch   = ws + 181120;
        float* wn2b[2] = { ws + 181376, ws + 181632 };
        float* wn2s = ws + 181888;
        float* Pn[2]  = { ws + 182144, ws + 182400 };
        float* phi[2] = { ws + 182656, ws + 183168 };
        float* cE[2]  = { ws + 183680, ws + 184192 };
        float* dE[2]  = { ws + 184704, ws + 185216 };
        int*   win[2] = { (int*)(ws + 185728), (int*)(ws + 186240) };
        float* S2[2]  = { ws + 186752, ws + 317824 };
        float* S0c    = ws + 448896;
        float* GxT[2] = { ws + 579968, ws + 842112 };
        float* Gw[2]  = { ws + 1104256, ws + 1366400 };

        hipMemcpyAsync(Wcur, W0, (size_t)NN * TS * sizeof(float),
                       hipMemcpyDeviceToDevice, stream);
        inv_kernel<<<N_EVENTS, 256, 0, stream>>>(ts, inv);
        init_kernel<<<2, 256, 0, stream>>>(chin, ch, Pn[0], Pn[1], phi[0], phi[1],
                                           cE[0], cE[1], dE[0], dE[1], win[0], win[1]);
        // prep: "materialize" W_{-1}=W_init, wn2base[0], S2(0)
        neuron_kernel<<<NN, 256, 0, stream>>>(ts, inv, Wcur, Wcur,
            win[1], phi[1], Pn[1], wn2b[0], S2[0], nullptr, nullptr,
            0, 0, 0, BATCH);
        gram_kernel<<<dim3(8, 8), 256, 0, stream>>>(ts, inv, Gw[0],
            0, BATCH, 0, BATCH, 1, 0);

        for (int b = 0; b < NB; ++b) {
            const int cs = b & 1, ps = 1 - cs;
            const int bstart = b * BATCH;
            const int bs = min(BATCH, N_EVENTS - bstart);
            const int bnext = bstart + BATCH;
            const int bsn = (b == NB - 1) ? 0 : min(BATCH, N_EVENTS - bnext);

            fix_kernel<<<BATCH, 256, 0, stream>>>(S2[cs], GxT[cs],
                win[ps], phi[ps], cE[ps], dE[ps], Pn[ps], wn2b[cs],
                S0c, wn2s, bs, (b == 0) ? 1 : 0);

            const int grid = (b == NB - 1) ? (NN + 1) : (NN + 1 + 100);
            fusedA_kernel<<<grid, 256, 0, stream>>>(ts, inv, S0c, Gw[cs],
                Gw[ps], GxT[ps], wn2s, ch,
                win[ps], phi[ps], Pn[ps],
                win[cs], phi[cs], cE[cs], dE[cs], Pn[cs],
                Wcur, wn2b[ps], S2[ps],
                out, b, bstart, bs, bnext, bsn);
        }
        // epilogue: materialize W_97 into out, copy ch
        neuron_kernel<<<NN, 256, 0, stream>>>(ts, inv, Wcur, out + N_EVENTS,
            win[1], phi[1], Pn[1], nullptr, nullptr, ch, out + N_EVENTS + NN * TS,
            97 * BATCH, 336, 0, 0);
    } else {
        // -------- fallback: round-2 proven path --------
        float* inv  = ws + 0;
        float* Wcur = ws + 50048;
        float* ch   = ws + 181120;
        float* wn2  = ws + 181376;
        float* rn   = ws + 181632;
        float* Pn   = ws + 181888;
        float* phi  = ws + 182144;
        int*   win  = (int*)(ws + 182656);
        float* S0P  = ws + 183168;
        float* G    = ws + 314240;

        hipMemcpyAsync(Wcur, W0, (size_t)NN * TS * sizeof(float),
                       hipMemcpyDeviceToDevice, stream);
        inv_kernel<<<N_EVENTS, 256, 0, stream>>>(ts, inv);
        winit_kernel<<<NN, 256, 0, stream>>>(Wcur, chin, ch, wn2, rn);

        for (int b = 0; b < NB; ++b) {
            int bstart = b * BATCH;
            int bs = min(BATCH, N_EVENTS - bstart);
            s0_gemm_kernel<<<dim3(8, 4), 256, 0, stream>>>(ts, Wcur, inv, S0P, bstart, bs);
            gram_kernel<<<dim3(8, 8), 256, 0, stream>>>(ts, inv, G,
                bstart, bs, bstart, bs, 1, 0);
            seq_step_kernel<<<1, 256, 0, stream>>>(S0P, G, ch, wn2, rn, Pn, phi, win,
                                                   out, bstart, bs);
            wupdate_kernel<<<NN, 256, 0, stream>>>(ts, inv, win, phi, Pn, Wcur,
                                                   wn2, rn, bstart, bs);
        }
        final_kernel<<<(NN * TS + NN + 255) / 256, 256, 0, stream>>>(Wcur, ch, out);
    }
}

// Round 4
// 53467.310 us; speedup vs baseline: 2.1287x; 1.5457x over previous
//
#include <hip/hip_runtime.h>
#include <hip/hip_bf16.h>

#define N_EVENTS 50000
#define TS 512
#define NN 256
#define BATCH 512
#define SUB 64
#define LAMB 0.25f
#define NB 98

#define RLF(v, l) __int_as_float(__builtin_amdgcn_readlane(__float_as_int(v), (l)))
#define RLI(v, l) __builtin_amdgcn_readlane((v), (l))
#define FRCP(x) __builtin_amdgcn_rcpf(x)
#define FRSQ(x) __builtin_amdgcn_rsqf(x)
#define DPP_MAXF(x, ctrl)                                                            \
    { int _s = __builtin_amdgcn_update_dpp(__float_as_int(x), __float_as_int(x),     \
                                           (ctrl), 0xF, 0xF, false);                 \
      (x) = fmaxf((x), __int_as_float(_s)); }

// ==================== shared small kernels ====================

__global__ __launch_bounds__(256)
void inv_kernel(const float* __restrict__ ts, float* __restrict__ inv)
{
    __shared__ double red[256];
    const int e = blockIdx.x;
    const int d = threadIdx.x;
    const float* row = ts + (size_t)e * TS;
    float x0 = row[d], x1 = row[d + 256];
    red[d] = (double)x0 * x0 + (double)x1 * x1;
    __syncthreads();
    for (int st = 128; st > 0; st >>= 1) {
        if (d < st) red[d] += red[d + st];
        __syncthreads();
    }
    if (d == 0) inv[e] = (float)(1.0 / sqrt(red[0]));
}

__global__ __launch_bounds__(256)
void init_kernel(const float* __restrict__ chin, float* __restrict__ ch,
                 float* Pn0, float* Pn1, float* phi0, float* phi1,
                 float* c0, float* c1, float* d0, float* d1,
                 int* w0, int* w1)
{
    int i = blockIdx.x * 256 + threadIdx.x;  // 0..511
    if (i < NN) { ch[i] = chin[i]; Pn0[i] = 1.f; Pn1[i] = 1.f; }
    if (i < BATCH) {
        phi0[i] = 0.f; phi1[i] = 0.f; c0[i] = 0.f; c1[i] = 0.f;
        d0[i] = 0.f; d1[i] = 0.f; w0[i] = 0; w1[i] = 0;
    }
}

// ==================== gram tile (device) ====================

__device__ void gram_tile(float* SH, const float* __restrict__ ts,
                          const float* __restrict__ inv,
                          int astart, int as, int bstart2, int bs2,
                          int be, int bf, float* __restrict__ outp, int transpose)
{
    float* At = SH;              // [64][33]
    float* Bt = SH + 64 * 33;
    if (be * 64 >= as || bf * 64 >= bs2) return;
    const int tx = threadIdx.x & 15, ty = threadIdx.x >> 4;
    float acc[4][4] = {};
    for (int kt = 0; kt < TS; kt += 32) {
        for (int it = threadIdx.x; it < 64 * 32; it += 256) {
            int r = it >> 5, c = it & 31;
            int ra = be * 64 + r, rb = bf * 64 + r;
            At[r * 33 + c] = (ra < as) ? ts[(size_t)(astart + ra) * TS + kt + c] : 0.f;
            Bt[r * 33 + c] = (rb < bs2) ? ts[(size_t)(bstart2 + rb) * TS + kt + c] : 0.f;
        }
        __syncthreads();
#pragma unroll
        for (int kk = 0; kk < 32; ++kk) {
            float av[4], bv[4];
#pragma unroll
            for (int i = 0; i < 4; ++i) av[i] = At[(ty * 4 + i) * 33 + kk];
#pragma unroll
            for (int j = 0; j < 4; ++j) bv[j] = Bt[(tx * 4 + j) * 33 + kk];
#pragma unroll
            for (int i = 0; i < 4; ++i)
#pragma unroll
                for (int j = 0; j < 4; ++j)
                    acc[i][j] += av[i] * bv[j];
        }
        __syncthreads();
    }
#pragma unroll
    for (int i = 0; i < 4; ++i) {
        int e = be * 64 + ty * 4 + i;
        if (e >= as) continue;
        float ie = inv[astart + e];
#pragma unroll
        for (int j = 0; j < 4; ++j) {
            int f = bf * 64 + tx * 4 + j;
            if (f >= bs2) continue;
            float v = acc[i][j] * ie * inv[bstart2 + f];
            if (transpose) outp[(size_t)f * BATCH + e] = v;
            else           outp[(size_t)e * BATCH + f] = v;
        }
    }
}

__global__ __launch_bounds__(256)
void gram_kernel(const float* __restrict__ ts, const float* __restrict__ inv,
                 float* __restrict__ outp, int astart, int as, int bstart2, int bs2,
                 int upper, int transpose)
{
    __shared__ float SHg[64 * 33 * 2];
    if (upper && (int)blockIdx.y < (int)blockIdx.x) return;
    gram_tile(SHg, ts, inv, astart, as, bstart2, bs2, blockIdx.x, blockIdx.y,
              outp, transpose);
}

// ==================== neuron body: wupdate + fused S2 ====================

__device__ void neuron_body(float* shf, double* red,
    const float* __restrict__ ts, const float* __restrict__ inv,
    const float* __restrict__ Wsrc, float* __restrict__ wdst,
    const int* __restrict__ winPrev, const float* __restrict__ phiPrev,
    const float* __restrict__ PnPrev,
    float* __restrict__ wn2W, float* __restrict__ S2W,
    const float* __restrict__ chbuf, float* __restrict__ chout,
    int n, int bprev_start, int bs_prev, int bnext_start, int bs_next)
{
    int* winS = (int*)shf;
    float* phiS = shf + 512;
    float* WL = shf + 1024;
    const int d = threadIdx.x;
    for (int i = d; i < bs_prev; i += 256) { winS[i] = winPrev[i]; phiS[i] = phiPrev[i]; }
    __syncthreads();
    const float Pf = PnPrev[n];
    float w0 = Wsrc[n * TS + d];
    float w1 = Wsrc[n * TS + d + 256];
    double a0 = 0.0, a1 = 0.0;
    for (int e = 0; e < bs_prev; ++e) {
        if (winS[e] == n) {
            double coef = (double)phiS[e];
            float iv = inv[bprev_start + e];
            const float* tr = ts + (size_t)(bprev_start + e) * TS;
            a0 += coef * (double)(tr[d] * iv);
            a1 += coef * (double)(tr[d + 256] * iv);
        }
    }
    w0 = (float)((double)Pf * ((double)w0 + a0));
    w1 = (float)((double)Pf * ((double)w1 + a1));
    wdst[n * TS + d] = w0;
    wdst[n * TS + d + 256] = w1;
    WL[d] = w0; WL[d + 256] = w1;
    if (wn2W) {
        red[d] = (double)w0 * w0 + (double)w1 * w1;
        __syncthreads();
        for (int st = 128; st > 0; st >>= 1) {
            if (d < st) red[d] += red[d + st];
            __syncthreads();
        }
        if (d == 0) wn2W[n] = (float)red[0];
    } else {
        __syncthreads();
    }
    if (bs_next > 0) {
#pragma unroll
        for (int rep = 0; rep < 2; ++rep) {
            int f = d + rep * 256;
            if (f < bs_next) {
                double acc = 0.0;
                const float* tr = ts + (size_t)(bnext_start + f) * TS;
                for (int k = 0; k < TS; ++k) acc += (double)tr[k] * (double)WL[k];
                S2W[f * NN + n] = (float)(acc * (double)inv[bnext_start + f]);
            }
        }
    }
    if (chout && d == 0) chout[n] = chbuf[n];
}

__global__ __launch_bounds__(256)
void neuron_kernel(const float* __restrict__ ts, const float* __restrict__ inv,
    const float* __restrict__ Wsrc, float* __restrict__ wdst,
    const int* __restrict__ winPrev, const float* __restrict__ phiPrev,
    const float* __restrict__ PnPrev,
    float* __restrict__ wn2W, float* __restrict__ S2W,
    const float* __restrict__ chbuf, float* __restrict__ chout,
    int bprev_start, int bs_prev, int bnext_start, int bs_next)
{
    __shared__ float SHN[1536];
    __shared__ double redN[256];
    neuron_body(SHN, redN, ts, inv, Wsrc, wdst, winPrev, phiPrev, PnPrev,
                wn2W, S2W, chbuf, chout, blockIdx.x,
                bprev_start, bs_prev, bnext_start, bs_next);
}

// ==================== fix kernel: S0corr + wn2 replay ====================

__global__ __launch_bounds__(256)
void fix_kernel(const float* __restrict__ S2r, const float* __restrict__ GxTr,
    const int* __restrict__ winPrev, const float* __restrict__ phiPrev,
    const float* __restrict__ cPrev, const float* __restrict__ dPrev,
    const float* __restrict__ PnPrev, const float* __restrict__ wn2b,
    float* __restrict__ S0corr, float* __restrict__ wn2start,
    int bs, int b0flag)
{
    __shared__ int winS[512];
    __shared__ float phiP[512];
    __shared__ float gr[512];
    __shared__ float cS[512];
    __shared__ float dS[512];
    const int tid = threadIdx.x;
    const int f = blockIdx.x;
    for (int i = tid; i < 512; i += 256) {
        int w = winPrev[i];
        winS[i] = w;
        phiP[i] = b0flag ? 0.f : phiPrev[i] * PnPrev[w];
        cS[i] = cPrev[i];
        dS[i] = dPrev[i];
        gr[i] = (b0flag || f >= bs) ? 0.f : GxTr[(size_t)f * BATCH + i];
    }
    __syncthreads();
    if (f < bs) {
        int n = tid;
        float acc = PnPrev[n] * S2r[f * NN + n];
        if (!b0flag) {
            for (int e = 0; e < 512; ++e)
                if (winS[e] == n) acc += phiP[e] * gr[e];
        }
        S0corr[f * NN + n] = acc;
    }
    if (f == 0 && tid < 64) {
        const int lane = tid;
        float w2[4];
#pragma unroll
        for (int k = 0; k < 4; ++k) w2[k] = wn2b[k * 64 + lane];
        for (int e = 0; e < 512; ++e) {
            float c = cS[e];
            if (c != 0.f) {
                int w = winS[e];
                int owner = w & 63, kk = w >> 6;
                float omc = 1.f - c;
                float t2 = 2.f * c * omc * dS[e] + c * c;
#pragma unroll
                for (int k = 0; k < 4; ++k)
                    if (lane == owner && k == kk) w2[k] = omc * omc * w2[k] + t2;
            }
        }
#pragma unroll
        for (int k = 0; k < 4; ++k) wn2start[k * 64 + lane] = w2[k];
    }
}

// ==================== block 0: sequential chain ====================

__device__ void block0_body(float* SH,
    const float* __restrict__ S0corr, const float* __restrict__ GwR,
    const float* __restrict__ wn2start, float* __restrict__ chbuf,
    int* __restrict__ winCur, float* __restrict__ phiCur,
    float* __restrict__ cCur, float* __restrict__ dotCur, float* __restrict__ PnCur,
    float* __restrict__ winners_out, int bstart, int bs)
{
    float* ACC = SH;                 // 16384 (swizzled col = (n+row)&255)
    float* GS  = SH + 16384;         // 4096
    float* GL  = SH + 20480;         // 4096
    int*   winL = (int*)(SH + 24576);// 512
    float* phiL = SH + 25088;        // 512
    float* cL   = SH + 25600;        // 512
    float* dL   = SH + 26112;        // 512
    const int tid = threadIdx.x, wid = tid >> 6, lane = tid & 63;

    const float KC = -(LAMB * 256.0f * 1.44269504f);
    float ch[4] = {0,0,0,0}, wn2v[4] = {1,1,1,1};
    float rn[4] = {1,1,1,1}, Pn[4] = {1,1,1,1}, al[4] = {0,0,0,0};
    float Ssum = 1.f, K2 = 0.f;
    if (wid == 0) {
#pragma unroll
        for (int k = 0; k < 4; ++k) {
            int n = k * 64 + lane;
            ch[k] = chbuf[n];
            wn2v[k] = wn2start[n];
            rn[k] = FRSQ(wn2v[k]);
            al[k] = 0.01f * FRCP(1.0f + ch[k] * (1.0f / 20000.0f));
        }
        float loc = ch[0] + ch[1] + ch[2] + ch[3];
#pragma unroll
        for (int off = 32; off > 0; off >>= 1) loc += __shfl_xor(loc, off, 64);
        Ssum = loc;
        K2 = KC * FRCP(Ssum);
    }

    const int nsub = (bs + SUB - 1) >> 6;
    for (int sub = 0; sub < nsub; ++sub) {
        const int s0 = sub << 6;
        const int cnt = min(SUB, bs - s0);
        __syncthreads();
        {   // stage corrected S0 (already P-folded) into ACC, 8-deep MLP
            const int n = tid;
            for (int f = 0; f < cnt; f += 8) {
                const float* src = S0corr + (size_t)(s0 + f) * NN + n;
                float v0 = src[0 * NN], v1 = src[1 * NN], v2 = src[2 * NN], v3 = src[3 * NN];
                float v4 = src[4 * NN], v5 = src[5 * NN], v6 = src[6 * NN], v7 = src[7 * NN];
                ACC[(f + 0) * NN + ((n + f + 0) & 255)] = v0;
                ACC[(f + 1) * NN + ((n + f + 1) & 255)] = v1;
                ACC[(f + 2) * NN + ((n + f + 2) & 255)] = v2;
                ACC[(f + 3) * NN + ((n + f + 3) & 255)] = v3;
                ACC[(f + 4) * NN + ((n + f + 4) & 255)] = v4;
                ACC[(f + 5) * NN + ((n + f + 5) & 255)] = v5;
                ACC[(f + 6) * NN + ((n + f + 6) & 255)] = v6;
                ACC[(f + 7) * NN + ((n + f + 7) & 255)] = v7;
            }
        }
        for (int it = tid; it < SUB * SUB; it += 256) {
            int t = it >> 6, f = it & 63;
            GS[it] = (t < cnt && f < cnt) ? GwR[(size_t)(s0 + t) * BATCH + s0 + f] : 0.f;
        }
        // within-batch lazy apply of earlier subs' events
        for (int base = 0; base < s0; base += 64) {
            {   // stage GL, 4-deep MLP
                const int i0 = tid, i1 = tid + 256, i2 = tid + 512, i3 = tid + 768;
                for (int rep = 0; rep < 4096; rep += 1024) {
                    float g0 = GwR[(size_t)(base + ((i0 + rep) >> 6)) * BATCH + s0 + (i0 & 63)];
                    float g1 = GwR[(size_t)(base + ((i1 + rep) >> 6)) * BATCH + s0 + (i1 & 63)];
                    float g2 = GwR[(size_t)(base + ((i2 + rep) >> 6)) * BATCH + s0 + (i2 & 63)];
                    float g3 = GwR[(size_t)(base + ((i3 + rep) >> 6)) * BATCH + s0 + (i3 & 63)];
                    GL[i0 + rep] = g0; GL[i1 + rep] = g1;
                    GL[i2 + rep] = g2; GL[i3 + rep] = g3;
                }
            }
            int wreg = winL[base + lane];
            float preg = phiL[base + lane];
            __syncthreads();
            for (int j = 0; j < 64; ++j) {
                int wj = RLI(wreg, j);
                if ((wj & 3) == wid) {
                    float pj = RLF(preg, j);
                    if (lane < cnt)
                        ACC[lane * NN + ((wj + lane) & 255)] += pj * GL[j * 64 + lane];
                }
            }
            __syncthreads();
        }
        __syncthreads();

        if (wid == 0) {
            float acur[4];
#pragma unroll
            for (int k = 0; k < 4; ++k) acur[k] = ACC[(k * 64 + lane) & 255];

            for (int t = 0; t < cnt; ++t) {
                const bool havenext = (t + 1 < cnt);
                float anext[4] = {0.f, 0.f, 0.f, 0.f};
                if (havenext) {
                    const int r = t + 1;
#pragma unroll
                    for (int k = 0; k < 4; ++k)
                        anext[k] = ACC[r * NN + ((k * 64 + lane + r) & 255)];
                }
                const int forig = t + 1 + lane;
                const float gval = GS[t * SUB + (forig & 63)];

                float beta[4], key[4];
#pragma unroll
                for (int k = 0; k < 4; ++k) {
                    float dot = Pn[k] * acur[k];
                    beta[k] = dot * rn[k];
                    key[k] = beta[k] * exp2f(K2 * ch[k]);
                }
                float kmax = fmaxf(fmaxf(key[0], key[1]), fmaxf(key[2], key[3]));
                DPP_MAXF(kmax, 0x111); DPP_MAXF(kmax, 0x112); DPP_MAXF(kmax, 0x114);
                DPP_MAXF(kmax, 0x118); DPP_MAXF(kmax, 0x142); DPP_MAXF(kmax, 0x143);
                const float smax = RLF(kmax, 63);

                unsigned long long m0 = __ballot(key[0] == smax);
                unsigned long long m1 = __ballot(key[1] == smax);
                unsigned long long m2 = __ballot(key[2] == smax);
                unsigned long long m3 = __ballot(key[3] == smax);
                int ns = m0 ? (int)__builtin_ctzll(m0)
                       : m1 ? 64  + (int)__builtin_ctzll(m1)
                       : m2 ? 128 + (int)__builtin_ctzll(m2)
                            : 192 + (int)__builtin_ctzll(m3);
                ns = __builtin_amdgcn_readfirstlane(ns);
                const int owner = ns & 63, ks = ns >> 6;

                float bsel = (ks == 0) ? beta[0] : (ks == 1) ? beta[1] : (ks == 2) ? beta[2] : beta[3];
                float asel = (ks == 0) ? acur[0] : (ks == 1) ? acur[1] : (ks == 2) ? acur[2] : acur[3];
                float psel = (ks == 0) ? Pn[0]   : (ks == 1) ? Pn[1]   : (ks == 2) ? Pn[2]   : Pn[3];
                float lsel = (ks == 0) ? al[0]   : (ks == 1) ? al[1]   : (ks == 2) ? al[2]   : al[3];
                const float betas  = RLF(bsel, owner);
                const float alphas = RLF(lsel, owner);
                const float dots   = RLF(psel * asel, owner);
                const float pold   = RLF(psel, owner);

                const float c    = alphas * betas;
                const float omc  = 1.0f - c;
                const float pnew = pold * omc;
                const float phi  = c * FRCP(pnew);
                const float g1   = RLF(gval, 0);

#pragma unroll
                for (int k = 0; k < 4; ++k) {
                    if (lane == owner && k == ks) {
                        wn2v[k] = omc * omc * wn2v[k] + 2.f * c * omc * dots + c * c;
                        rn[k] = FRSQ(wn2v[k]);
                        ch[k] += 1.0f;
                        al[k] = 0.01f * FRCP(1.0f + ch[k] * (1.0f / 20000.0f));
                        Pn[k] = pnew;
                        anext[k] += phi * g1;
                    }
                }
                if (lane > 0 && forig < cnt)
                    ACC[forig * NN + ((ns + forig) & 255)] += phi * gval;

                const int ib = s0 + t;
                if (lane == 0) {
                    winL[ib] = ns; phiL[ib] = phi;
                    cL[ib] = c; dL[ib] = dots;
                }
                Ssum += 1.0f;
                K2 = KC * FRCP(Ssum);
                if (havenext) {
#pragma unroll
                    for (int k = 0; k < 4; ++k) acur[k] = anext[k];
                }
            }
        }
    }
    __syncthreads();
    if (wid == 0) {
#pragma unroll
        for (int k = 0; k < 4; ++k) {
            int n = k * 64 + lane;
            chbuf[n] = ch[k];
            PnCur[n] = Pn[k];
        }
    }
    // batched flush of per-event outputs (all threads)
    for (int i = tid; i < bs; i += 256) {
        int w = winL[i];
        winCur[i] = w;
        phiCur[i] = phiL[i];
        cCur[i] = cL[i];
        dotCur[i] = dL[i];
        winners_out[bstart + i] = (float)w;
    }
}

// ==================== fused per-batch kernel ====================

__global__ __launch_bounds__(256)
void fusedA_kernel(const float* __restrict__ ts, const float* __restrict__ inv,
    const float* __restrict__ S0corr, const float* __restrict__ GwR,
    float* __restrict__ GwW, float* __restrict__ GxTW,
    const float* __restrict__ wn2start, float* __restrict__ chbuf,
    const int* __restrict__ winPrev, const float* __restrict__ phiPrev,
    const float* __restrict__ PnPrev,
    int* __restrict__ winCur, float* __restrict__ phiCur,
    float* __restrict__ cCur, float* __restrict__ dotCur, float* __restrict__ PnCur,
    float* __restrict__ Wcur, float* __restrict__ wn2W, float* __restrict__ S2W,
    float* __restrict__ out, int b, int bstart, int bs, int bnext_start, int bs_next)
{
    __shared__ float SH[26624];
    const int bx = blockIdx.x;
    if (bx == 0) {
        block0_body(SH, S0corr, GwR, wn2start, chbuf,
                    winCur, phiCur, cCur, dotCur, PnCur, out, bstart, bs);
    } else if (bx <= NN) {
        neuron_body(SH, (double*)(SH + 1536), ts, inv, Wcur, Wcur,
                    winPrev, phiPrev, PnPrev, wn2W, S2W, nullptr, nullptr,
                    bx - 1, bstart - BATCH, (b == 0) ? 0 : BATCH,
                    bnext_start, bs_next);
    } else {
        int job = bx - (NN + 1);  // 0..99
        if (bs_next <= 0) return;
        if (job < 64) {
            gram_tile(SH, ts, inv, bstart, bs, bnext_start, bs_next,
                      job >> 3, job & 7, GxTW, 1);
        } else {
            int jw = job - 64;
            int be = 0;
            while (jw >= 8 - be) { jw -= 8 - be; ++be; }
            int bf = be + jw;
            gram_tile(SH, ts, inv, bnext_start, bs_next, bnext_start, bs_next,
                      be, bf, GwW, 0);
        }
    }
}

// ==================== fallback path (round-2, proven) ====================

__global__ __launch_bounds__(256)
void winit_kernel(const float* __restrict__ Wcur, const float* __restrict__ chin,
                  float* __restrict__ ch, float* __restrict__ wn2, float* __restrict__ rn)
{
    __shared__ double red[256];
    const int n = blockIdx.x;
    const int d = threadIdx.x;
    float w0 = Wcur[n * TS + d], w1 = Wcur[n * TS + d + 256];
    red[d] = (double)w0 * w0 + (double)w1 * w1;
    __syncthreads();
    for (int st = 128; st > 0; st >>= 1) {
        if (d < st) red[d] += red[d + st];
        __syncthreads();
    }
    if (d == 0) {
        double s = red[0];
        wn2[n] = (float)s;
        rn[n]  = (float)(1.0 / sqrt(s));
        ch[n]  = chin[n];
    }
}

__global__ __launch_bounds__(256)
void s0_gemm_kernel(const float* __restrict__ ts, const float* __restrict__ Wcur,
                    const float* __restrict__ inv, float* __restrict__ S0P,
                    int bstart, int bs)
{
    __shared__ float At[64][33];
    __shared__ float Bt[64][33];
    const int bf = blockIdx.x;
    const int bn = blockIdx.y;
    if (bf * 64 >= bs) return;
    const int tx = threadIdx.x & 15, ty = threadIdx.x >> 4;
    double acc[4][4] = {};
    for (int kt = 0; kt < TS; kt += 32) {
        for (int it = threadIdx.x; it < 64 * 32; it += 256) {
            int r = it >> 5, c = it & 31;
            int row = bf * 64 + r;
            At[r][c] = (row < bs) ? ts[(size_t)(bstart + row) * TS + kt + c] : 0.f;
            Bt[r][c] = Wcur[(bn * 64 + r) * TS + kt + c];
        }
        __syncthreads();
#pragma unroll
        for (int kk = 0; kk < 32; ++kk) {
            float av[4], bv[4];
#pragma unroll
            for (int i = 0; i < 4; ++i) av[i] = At[ty * 4 + i][kk];
#pragma unroll
            for (int j = 0; j < 4; ++j) bv[j] = Bt[tx * 4 + j][kk];
#pragma unroll
            for (int i = 0; i < 4; ++i)
#pragma unroll
                for (int j = 0; j < 4; ++j)
                    acc[i][j] += (double)av[i] * (double)bv[j];
        }
        __syncthreads();
    }
#pragma unroll
    for (int i = 0; i < 4; ++i) {
        int f = bf * 64 + ty * 4 + i;
        if (f >= bs) continue;
        double iv = (double)inv[bstart + f];
#pragma unroll
        for (int j = 0; j < 4; ++j) {
            int n = bn * 64 + tx * 4 + j;
            S0P[f * NN + n] = (float)(acc[i][j] * iv);
        }
    }
}

__global__ __launch_bounds__(256)
void seq_step_kernel(const float* __restrict__ S0P, const float* __restrict__ Gb,
                     float* __restrict__ ch_g, const float* __restrict__ wn2_g,
                     const float* __restrict__ rn_g, float* __restrict__ Pn_g,
                     float* __restrict__ phi_g, int* __restrict__ win_g,
                     float* __restrict__ winners_out, int bstart, int bs)
{
    __shared__ float ACC[SUB * NN];
    __shared__ float GS[SUB * SUB];
    __shared__ float GL[SUB * SUB];
    __shared__ int   winL[BATCH];
    __shared__ float phiL[BATCH];

    const int tid = threadIdx.x;
    const int wid = tid >> 6;
    const int lane = tid & 63;

    float ch[4] = {0, 0, 0, 0}, wn2v[4] = {1, 1, 1, 1};
    float rn[4] = {1, 1, 1, 1}, Pn[4] = {1, 1, 1, 1};
    float Ssum = 1.f, sinv = 1.f;
    if (wid == 0) {
#pragma unroll
        for (int k = 0; k < 4; ++k) {
            int n = k * 64 + lane;
            ch[k]   = ch_g[n];
            wn2v[k] = wn2_g[n];
            rn[k]   = rn_g[n];
            Pn[k]   = 1.0f;
        }
        float loc = ch[0] + ch[1] + ch[2] + ch[3];
#pragma unroll
        for (int off = 32; off > 0; off >>= 1) loc += __shfl_xor(loc, off, 64);
        Ssum = loc;
        sinv = 1.0f / Ssum;
    }

    const int nsub = (bs + SUB - 1) >> 6;
    for (int sub = 0; sub < nsub; ++sub) {
        const int s0 = sub << 6;
        const int cnt = min(SUB, bs - s0);
        __syncthreads();

        for (int it = tid; it < cnt * NN; it += 256) {
            int r = it >> 8, n = it & 255;
            ACC[r * NN + ((n + r) & 255)] = S0P[(s0 + r) * NN + n];
        }
        for (int it = tid; it < cnt * SUB; it += 256) {
            int t = it >> 6, f = it & 63;
            GS[t * SUB + f] = (f < cnt) ? Gb[(s0 + t) * BATCH + s0 + f] : 0.f;
        }
        __syncthreads();

        for (int base = 0; base < s0; base += 64) {
            for (int it = tid; it < 64 * 64; it += 256)
                GL[it] = Gb[(base + (it >> 6)) * BATCH + s0 + (it & 63)];
            int   wreg = winL[base + lane];
            float preg = phiL[base + lane];
            __syncthreads();
            for (int j = 0; j < 64; ++j) {
                int wj = RLI(wreg, j);
                if ((wj & 3) == wid) {
                    float pj = RLF(preg, j);
                    if (lane < cnt)
                        ACC[lane * NN + ((wj + lane) & 255)] += pj * GL[j * 64 + lane];
                }
            }
            __syncthreads();
        }

        if (wid == 0) {
            float acur[4];
#pragma unroll
            for (int k = 0; k < 4; ++k) acur[k] = ACC[(k * 64 + lane) & 255];

            for (int t = 0; t < cnt; ++t) {
                const bool havenext = (t + 1 < cnt);
                float anext[4] = {0.f, 0.f, 0.f, 0.f};
                if (havenext) {
                    const int r = t + 1;
#pragma unroll
                    for (int k = 0; k < 4; ++k)
                        anext[k] = ACC[r * NN + ((k * 64 + lane + r) & 255)];
                }
                const int forig = t + 1 + lane;
                const float gval = GS[t * SUB + (forig & 63)];

                const float gmul = 256.0f * sinv;
                float beta[4], key[4];
                float kmax;
#pragma unroll
                for (int k = 0; k < 4; ++k) {
                    float dot = Pn[k] * acur[k];
                    beta[k] = dot * rn[k];
                    float frac = ch[k] * gmul;
                    float gain = __expf(LAMB * (1.0f - frac));
                    key[k] = gain * beta[k];
                }
                kmax = fmaxf(fmaxf(key[0], key[1]), fmaxf(key[2], key[3]));
                DPP_MAXF(kmax, 0x111); DPP_MAXF(kmax, 0x112); DPP_MAXF(kmax, 0x114);
                DPP_MAXF(kmax, 0x118); DPP_MAXF(kmax, 0x142); DPP_MAXF(kmax, 0x143);
                const float smax = RLF(kmax, 63);

                unsigned long long m0 = __ballot(key[0] == smax);
                unsigned long long m1 = __ballot(key[1] == smax);
                unsigned long long m2 = __ballot(key[2] == smax);
                unsigned long long m3 = __ballot(key[3] == smax);
                int ns = m0 ? (int)__builtin_ctzll(m0)
                       : m1 ? 64  + (int)__builtin_ctzll(m1)
                       : m2 ? 128 + (int)__builtin_ctzll(m2)
                            : 192 + (int)__builtin_ctzll(m3);
                ns = __builtin_amdgcn_readfirstlane(ns);
                const int owner = ns & 63, ks = ns >> 6;

                float bsel = (ks == 0) ? beta[0] : (ks == 1) ? beta[1] : (ks == 2) ? beta[2] : beta[3];
                float csel = (ks == 0) ? ch[0]   : (ks == 1) ? ch[1]   : (ks == 2) ? ch[2]   : ch[3];
                float asel = (ks == 0) ? acur[0] : (ks == 1) ? acur[1] : (ks == 2) ? acur[2] : acur[3];
                float psel = (ks == 0) ? Pn[0]   : (ks == 1) ? Pn[1]   : (ks == 2) ? Pn[2]   : Pn[3];
                const float betas = RLF(bsel, owner);
                const float chs   = RLF(csel, owner);
                const float dots  = RLF(psel * asel, owner);
                const float pold  = RLF(psel, owner);

                const float alpha = 0.01f / (1.0f + chs / 20000.0f);
                const float c    = alpha * betas;
                const float omc  = 1.0f - c;
                const float pnew = pold * omc;
                const float phi  = c / pnew;
                const float g1   = RLF(gval, 0);

#pragma unroll
                for (int k = 0; k < 4; ++k) {
                    bool me = (lane == owner) && (k == ks);
                    if (me) {
                        wn2v[k] = omc * omc * wn2v[k] + 2.f * c * omc * dots + c * c;
                        rn[k] = 1.0f / sqrtf(wn2v[k]);
                        ch[k] += 1.0f;
                        Pn[k] = pnew;
                        anext[k] += phi * g1;
                    }
                }
                if (lane > 0 && forig < cnt)
                    ACC[forig * NN + ((ns + forig) & 255)] += phi * gval;

                const int ib = s0 + t;
                if (lane == 0) {
                    winL[ib] = ns; phiL[ib] = phi;
                    win_g[ib] = ns; phi_g[ib] = phi;
                    winners_out[bstart + ib] = (float)ns;
                }
                Ssum += 1.0f;
                sinv = 1.0f / Ssum;
                if (havenext) {
#pragma unroll
                    for (int k = 0; k < 4; ++k) acur[k] = anext[k];
                }
            }
        }
        __syncthreads();
    }

    if (wid == 0) {
#pragma unroll
        for (int k = 0; k < 4; ++k) {
            int n = k * 64 + lane;
            ch_g[n] = ch[k];
            Pn_g[n] = Pn[k];
        }
    }
}

__global__ __launch_bounds__(256)
void wupdate_kernel(const float* __restrict__ ts, const float* __restrict__ inv,
                    const int* __restrict__ win_g, const float* __restrict__ phi_g,
                    const float* __restrict__ Pn_g, float* __restrict__ Wcur,
                    float* __restrict__ wn2_g, float* __restrict__ rn_g,
                    int bstart, int bs)
{
    __shared__ int   winS[BATCH];
    __shared__ float phiS[BATCH];
    __shared__ double red[256];
    const int n = blockIdx.x;
    const int d = threadIdx.x;
    for (int i = d; i < bs; i += 256) { winS[i] = win_g[i]; phiS[i] = phi_g[i]; }
    __syncthreads();
    const float Pf = Pn_g[n];
    float w0 = Wcur[n * TS + d];
    float w1 = Wcur[n * TS + d + 256];
    double a0 = 0.0, a1 = 0.0;
    for (int ib = 0; ib < bs; ++ib) {
        if (winS[ib] == n) {
            double coef = (double)phiS[ib] * (double)Pf;
            float iv = inv[bstart + ib];
            const float* tr = ts + (size_t)(bstart + ib) * TS;
            a0 += coef * (double)(tr[d] * iv);
            a1 += coef * (double)(tr[d + 256] * iv);
        }
    }
    w0 = (float)((double)Pf * (double)w0 + a0);
    w1 = (float)((double)Pf * (double)w1 + a1);
    Wcur[n * TS + d] = w0;
    Wcur[n * TS + d + 256] = w1;
    red[d] = (double)w0 * w0 + (double)w1 * w1;
    __syncthreads();
    for (int st = 128; st > 0; st >>= 1) {
        if (d < st) red[d] += red[d + st];
        __syncthreads();
    }
    if (d == 0) {
        double s = red[0];
        wn2_g[n] = (float)s;
        rn_g[n]  = (float)(1.0 / sqrt(s));
    }
}

__global__ __launch_bounds__(256)
void final_kernel(const float* __restrict__ Wcur, const float* __restrict__ ch,
                  float* __restrict__ out)
{
    int i = blockIdx.x * 256 + threadIdx.x;
    if (i < NN * TS) out[N_EVENTS + i] = Wcur[i];
    else if (i < NN * TS + NN) out[N_EVENTS + i] = ch[i - NN * TS];
}

// ==================== host ====================

extern "C" void kernel_launch(void* const* d_in, const int* in_sizes, int n_in,
                              void* d_out, int out_size, void* d_ws, size_t ws_size,
                              hipStream_t stream)
{
    const float* ts   = (const float*)d_in[0];
    const float* W0   = (const float*)d_in[1];
    const float* chin = (const float*)d_in[2];
    float* out = (float*)d_out;
    float* ws  = (float*)d_ws;

    const size_t FULL_FLOATS = 1628544;  // ~6.52 MB
    if (ws_size >= FULL_FLOATS * sizeof(float)) {
        // -------- full pipelined path --------
        float* inv  = ws + 0;
        float* Wcur = ws + 50048;
        float* ch   = ws + 181120;
        float* wn2b[2] = { ws + 181376, ws + 181632 };
        float* wn2s = ws + 181888;
        float* Pn[2]  = { ws + 182144, ws + 182400 };
        float* phi[2] = { ws + 182656, ws + 183168 };
        float* cE[2]  = { ws + 183680, ws + 184192 };
        float* dE[2]  = { ws + 184704, ws + 185216 };
        int*   win[2] = { (int*)(ws + 185728), (int*)(ws + 186240) };
        float* S2[2]  = { ws + 186752, ws + 317824 };
        float* S0c    = ws + 448896;
        float* GxT[2] = { ws + 579968, ws + 842112 };
        float* Gw[2]  = { ws + 1104256, ws + 1366400 };

        hipMemcpyAsync(Wcur, W0, (size_t)NN * TS * sizeof(float),
                       hipMemcpyDeviceToDevice, stream);
        inv_kernel<<<N_EVENTS, 256, 0, stream>>>(ts, inv);
        init_kernel<<<2, 256, 0, stream>>>(chin, ch, Pn[0], Pn[1], phi[0], phi[1],
                                           cE[0], cE[1], dE[0], dE[1], win[0], win[1]);
        // prep: "materialize" W_{-1}=W_init, wn2base[0], S2(0)
        neuron_kernel<<<NN, 256, 0, stream>>>(ts, inv, Wcur, Wcur,
            win[1], phi[1], Pn[1], wn2b[0], S2[0], nullptr, nullptr,
            0, 0, 0, BATCH);
        gram_kernel<<<dim3(8, 8), 256, 0, stream>>>(ts, inv, Gw[0],
            0, BATCH, 0, BATCH, 1, 0);

        for (int b = 0; b < NB; ++b) {
            const int cs = b & 1, ps = 1 - cs;
            const int bstart = b * BATCH;
            const int bs = min(BATCH, N_EVENTS - bstart);
            const int bnext = bstart + BATCH;
            const int bsn = (b == NB - 1) ? 0 : min(BATCH, N_EVENTS - bnext);

            fix_kernel<<<BATCH, 256, 0, stream>>>(S2[cs], GxT[cs],
                win[ps], phi[ps], cE[ps], dE[ps], Pn[ps], wn2b[cs],
                S0c, wn2s, bs, (b == 0) ? 1 : 0);

            const int grid = (b == NB - 1) ? (NN + 1) : (NN + 1 + 100);
            fusedA_kernel<<<grid, 256, 0, stream>>>(ts, inv, S0c, Gw[cs],
                Gw[ps], GxT[ps], wn2s, ch,
                win[ps], phi[ps], Pn[ps],
                win[cs], phi[cs], cE[cs], dE[cs], Pn[cs],
                Wcur, wn2b[ps], S2[ps],
                out, b, bstart, bs, bnext, bsn);
        }
        // epilogue: materialize W_97 into out, copy ch
        neuron_kernel<<<NN, 256, 0, stream>>>(ts, inv, Wcur, out + N_EVENTS,
            win[1], phi[1], Pn[1], nullptr, nullptr, ch, out + N_EVENTS + NN * TS,
            97 * BATCH, 336, 0, 0);
    } else {
        // -------- fallback: round-2 proven path --------
        float* inv  = ws + 0;
        float* Wcur = ws + 50048;
        float* ch   = ws + 181120;
        float* wn2  = ws + 181376;
        float* rn   = ws + 181632;
        float* Pn   = ws + 181888;
        float* phi  = ws + 182144;
        int*   win  = (int*)(ws + 182656);
        float* S0P  = ws + 183168;
        float* G    = ws + 314240;

        hipMemcpyAsync(Wcur, W0, (size_t)NN * TS * sizeof(float),
                       hipMemcpyDeviceToDevice, stream);
        inv_kernel<<<N_EVENTS, 256, 0, stream>>>(ts, inv);
        winit_kernel<<<NN, 256, 0, stream>>>(Wcur, chin, ch, wn2, rn);

        for (int b = 0; b < NB; ++b) {
            int bstart = b * BATCH;
            int bs = min(BATCH, N_EVENTS - bstart);
            s0_gemm_kernel<<<dim3(8, 4), 256, 0, stream>>>(ts, Wcur, inv, S0P, bstart, bs);
            gram_kernel<<<dim3(8, 8), 256, 0, stream>>>(ts, inv, G,
                bstart, bs, bstart, bs, 1, 0);
            seq_step_kernel<<<1, 256, 0, stream>>>(S0P, G, ch, wn2, rn, Pn, phi, win,
                                                   out, bstart, bs);
            wupdate_kernel<<<NN, 256, 0, stream>>>(ts, inv, win, phi, Pn, Wcur,
                                                   wn2, rn, bstart, bs);
        }
        final_kernel<<<(NN * TS + NN + 255) / 256, 256, 0, stream>>>(Wcur, ch, out);
    }
}